// Round 7
// baseline (100.901 us; speedup 1.0000x reference)
//
#include <hip/hip_runtime.h>

#define S_DIM 64
#define B_DIM 128
#define D_DIM 10000
#define NV4   2500          // D_DIM / 4
#define BLOCK 256
#define KMAX  10            // ceil(NV4/BLOCK); k<9 always valid, k==9 iff tid<196
#define RPB   4             // noise rows (s values) per block, same b
#define NBLK  ((S_DIM / RPB) * B_DIM)   // 2048
#define NROWS (S_DIM * B_DIM)

// Algebraic single-pass form:  sum_d (e_d/S - y_d)^2 = Q/S^2 - 2P/S + Y2
// with S = sum e, Q = sum e^2, P = sum e*y, Y2 = sum y^2, e = exp(theta+noise).
// No persisted exp row -> theta & y held in registers across RPB=4 noise rows
// (loaded once per block, cutting theta/y traffic 4x; pass-2 y walk removed).
// Max-subtraction skipped: eta ~ N(0,sqrt(2)), dataset max ~8.5, exp safe in
// fp32; softmax shift-invariant. Rounds 4/5 lesson: no min-wave clamp (spill),
// and #pragma unroll 1 on the row loop so noise loads for 4 rows don't hoist.
__global__ __launch_bounds__(BLOCK) void perturbed_loss_multirow(
    const float* __restrict__ theta,   // [B, D]
    const float* __restrict__ y,       // [B, D]
    const float* __restrict__ noise,   // [S, B, D]
    float* __restrict__ partials)      // [NBLK] per-block SSE sums
{
    __shared__ float redS[4], redQ[4], redP[4];

    const int blk  = blockIdx.x;           // [0, NBLK)
    const int b    = blk >> 4;             // blk / 16  -> [0,128)
    const int s0   = (blk & 15) * RPB;     // [0,64) step 4
    const int tid  = threadIdx.x;
    const int lane = tid & 63;
    const int wave = tid >> 6;

    const float4* th4 = reinterpret_cast<const float4*>(theta + (size_t)b * D_DIM);
    const float4* y4  = reinterpret_cast<const float4*>(y     + (size_t)b * D_DIM);

    // ---- Load theta & y rows into registers (once per block) ----
    float4 t[KMAX], yv[KMAX];
    float y2 = 0.0f;
    #pragma unroll
    for (int k = 0; k < KMAX; ++k) {
        const int i = tid + k * BLOCK;
        if (k < KMAX - 1 || i < NV4) {
            t[k]  = th4[i];
            yv[k] = y4[i];
            y2 += (yv[k].x * yv[k].x + yv[k].y * yv[k].y)
                + (yv[k].z * yv[k].z + yv[k].w * yv[k].w);
        }
    }

    // ---- Stream RPB noise rows, accumulating S, Q, P per row ----
    float loss_acc = 0.0f;                 // only tid 0's copy is used
    #pragma unroll 1
    for (int r = 0; r < RPB; ++r) {
        const float4* nz4 = reinterpret_cast<const float4*>(
            noise + ((size_t)(s0 + r) * B_DIM + b) * D_DIM);
        float sm = 0.0f, q = 0.0f, p = 0.0f;
        #pragma unroll
        for (int k = 0; k < KMAX; ++k) {
            const int i = tid + k * BLOCK;
            if (k < KMAX - 1 || i < NV4) {
                float4 n = nz4[i];
                float ex = __expf(t[k].x + n.x);
                float ey = __expf(t[k].y + n.y);
                float ez = __expf(t[k].z + n.z);
                float ew = __expf(t[k].w + n.w);
                sm += (ex + ey) + (ez + ew);
                q  = fmaf(ex, ex, q); q = fmaf(ey, ey, q);
                q  = fmaf(ez, ez, q); q = fmaf(ew, ew, q);
                p  = fmaf(ex, yv[k].x, p); p = fmaf(ey, yv[k].y, p);
                p  = fmaf(ez, yv[k].z, p); p = fmaf(ew, yv[k].w, p);
            }
        }
        #pragma unroll
        for (int o = 32; o > 0; o >>= 1) {
            sm += __shfl_down(sm, o, 64);
            q  += __shfl_down(q,  o, 64);
            p  += __shfl_down(p,  o, 64);
        }
        if (lane == 0) { redS[wave] = sm; redQ[wave] = q; redP[wave] = p; }
        __syncthreads();
        if (tid == 0) {
            float St = (redS[0] + redS[1]) + (redS[2] + redS[3]);
            float Qt = (redQ[0] + redQ[1]) + (redQ[2] + redQ[3]);
            float Pt = (redP[0] + redP[1]) + (redP[2] + redP[3]);
            float invS = 1.0f / St;
            loss_acc += Qt * invS * invS - 2.0f * Pt * invS;
        }
        __syncthreads();                   // red* reused next iteration
    }

    // ---- Block Y2 reduction (once), then write partial ----
    #pragma unroll
    for (int o = 32; o > 0; o >>= 1) y2 += __shfl_down(y2, o, 64);
    if (lane == 0) redS[wave] = y2;
    __syncthreads();
    if (tid == 0) {
        float Y2t = (redS[0] + redS[1]) + (redS[2] + redS[3]);
        partials[blk] = loss_acc + (float)RPB * Y2t;
    }
}

// Deterministic fixed-order reduction of the per-block partials.
__global__ __launch_bounds__(BLOCK) void reduce_partials(
    const float* __restrict__ partials,
    float* __restrict__ out)
{
    __shared__ double red[4];
    const int tid  = threadIdx.x;
    const int lane = tid & 63;
    const int wave = tid >> 6;

    double s = 0.0;
    for (int i = tid; i < NBLK; i += BLOCK) s += (double)partials[i];
    #pragma unroll
    for (int o = 32; o > 0; o >>= 1) s += __shfl_down(s, o, 64);
    if (lane == 0) red[wave] = s;
    __syncthreads();
    if (tid == 0) {
        double t = ((red[0] + red[1]) + (red[2] + red[3]));
        out[0] = (float)(t / ((double)S_DIM * (double)B_DIM * (double)D_DIM));
    }
}

extern "C" void kernel_launch(void* const* d_in, const int* in_sizes, int n_in,
                              void* d_out, int out_size, void* d_ws, size_t ws_size,
                              hipStream_t stream) {
    const float* theta = (const float*)d_in[0];
    const float* y     = (const float*)d_in[1];
    const float* noise = (const float*)d_in[2];
    float* out      = (float*)d_out;
    float* partials = (float*)d_ws;   // NBLK floats = 8 KB scratch

    perturbed_loss_multirow<<<NBLK, BLOCK, 0, stream>>>(theta, y, noise, partials);
    reduce_partials<<<1, BLOCK, 0, stream>>>(partials, out);
}

// Round 8
// 94.250 us; speedup vs baseline: 1.0706x; 1.0706x over previous
//
#include <hip/hip_runtime.h>

#define S_DIM 64
#define B_DIM 128
#define D_DIM 10000
#define NV4   2500          // D_DIM / 4
#define BLOCK 256
#define KMAX  10            // ceil(NV4/BLOCK); k<9 always valid, k==9 iff tid<196
#define NROWS (S_DIM * B_DIM)

// Single-pass streaming form: per row (s,b),
//   loss = Q/S^2 - 2P/S + Y2,  S=sum e, Q=sum e^2, P=sum e*y, Y2=sum y^2,
//   e = exp(theta+noise).
// Kernel 1 is a PURE streaming reduce: no persisted exp row (round 2's 40
// VGPR ex[]), no register-pinned theta/y (round 7's 80 VGPR, 100.9us), no
// mid-kernel barriers. Minimal live state -> max occupancy -> max noise
// loads in flight (we are HBM-latency/MLP-bound; floor ~52us).
// Max-subtraction skipped: eta ~ N(0,sqrt(2)), dataset max ~8.5, exp safe in
// fp32; softmax shift-invariant. All nonlinear per-row math deferred to the
// tiny kernel 2 (deterministic fixed-order double accumulation).
__global__ __launch_bounds__(BLOCK) void perturbed_loss_stream(
    const float* __restrict__ theta,   // [B, D]
    const float* __restrict__ y,       // [B, D]
    const float* __restrict__ noise,   // [S, B, D]
    float4* __restrict__ partials)     // [NROWS] = {S, Q, P, Y2}
{
    __shared__ float redS[4], redQ[4], redP[4], redY[4];

    const int blk  = blockIdx.x;           // row id in [0, NROWS)
    const int b    = blk % B_DIM;
    const int tid  = threadIdx.x;
    const int lane = tid & 63;
    const int wave = tid >> 6;

    const float4* th4 = reinterpret_cast<const float4*>(theta + (size_t)b * D_DIM);
    const float4* y4  = reinterpret_cast<const float4*>(y     + (size_t)b * D_DIM);
    const float4* nz4 = reinterpret_cast<const float4*>(noise + (size_t)blk * D_DIM);

    float s = 0.0f, q = 0.0f, p = 0.0f, y2 = 0.0f;
    #pragma unroll
    for (int k = 0; k < KMAX; ++k) {
        const int i = tid + k * BLOCK;
        if (k < KMAX - 1 || i < NV4) {
            float4 t  = th4[i];
            float4 n  = nz4[i];
            float4 yy = y4[i];
            float ex = __expf(t.x + n.x);
            float ey = __expf(t.y + n.y);
            float ez = __expf(t.z + n.z);
            float ew = __expf(t.w + n.w);
            s += (ex + ey) + (ez + ew);
            q = fmaf(ex, ex, q); q = fmaf(ey, ey, q);
            q = fmaf(ez, ez, q); q = fmaf(ew, ew, q);
            p = fmaf(ex, yy.x, p); p = fmaf(ey, yy.y, p);
            p = fmaf(ez, yy.z, p); p = fmaf(ew, yy.w, p);
            y2 = fmaf(yy.x, yy.x, y2); y2 = fmaf(yy.y, yy.y, y2);
            y2 = fmaf(yy.z, yy.z, y2); y2 = fmaf(yy.w, yy.w, y2);
        }
    }
    #pragma unroll
    for (int o = 32; o > 0; o >>= 1) {
        s  += __shfl_down(s,  o, 64);
        q  += __shfl_down(q,  o, 64);
        p  += __shfl_down(p,  o, 64);
        y2 += __shfl_down(y2, o, 64);
    }
    if (lane == 0) { redS[wave] = s; redQ[wave] = q; redP[wave] = p; redY[wave] = y2; }
    __syncthreads();
    if (tid == 0) {
        float4 r;
        r.x = (redS[0] + redS[1]) + (redS[2] + redS[3]);
        r.y = (redQ[0] + redQ[1]) + (redQ[2] + redQ[3]);
        r.z = (redP[0] + redP[1]) + (redP[2] + redP[3]);
        r.w = (redY[0] + redY[1]) + (redY[2] + redY[3]);
        partials[blk] = r;
    }
}

// Deterministic fixed-order combine: per-row loss then global mean (double).
__global__ __launch_bounds__(BLOCK) void reduce_partials(
    const float4* __restrict__ partials,
    float* __restrict__ out)
{
    __shared__ double red[4];
    const int tid  = threadIdx.x;
    const int lane = tid & 63;
    const int wave = tid >> 6;

    double acc = 0.0;
    for (int i = tid; i < NROWS; i += BLOCK) {   // fixed order per thread
        float4 r = partials[i];
        double S = (double)r.x, Q = (double)r.y, P = (double)r.z, Y2 = (double)r.w;
        double invS = 1.0 / S;
        acc += (Q * invS - 2.0 * P) * invS + Y2;
    }
    #pragma unroll
    for (int o = 32; o > 0; o >>= 1) acc += __shfl_down(acc, o, 64);
    if (lane == 0) red[wave] = acc;
    __syncthreads();
    if (tid == 0) {
        double t = ((red[0] + red[1]) + (red[2] + red[3]));
        out[0] = (float)(t / ((double)S_DIM * (double)B_DIM * (double)D_DIM));
    }
}

extern "C" void kernel_launch(void* const* d_in, const int* in_sizes, int n_in,
                              void* d_out, int out_size, void* d_ws, size_t ws_size,
                              hipStream_t stream) {
    const float* theta = (const float*)d_in[0];
    const float* y     = (const float*)d_in[1];
    const float* noise = (const float*)d_in[2];
    float* out       = (float*)d_out;
    float4* partials = (float4*)d_ws;   // NROWS float4 = 128 KB scratch

    perturbed_loss_stream<<<NROWS, BLOCK, 0, stream>>>(theta, y, noise, partials);
    reduce_partials<<<1, BLOCK, 0, stream>>>(partials, out);
}

// Round 9
// 81.304 us; speedup vs baseline: 1.2410x; 1.1592x over previous
//
#include <hip/hip_runtime.h>

#define S_DIM 64
#define B_DIM 128
#define D_DIM 10000
#define NV4   2500          // D_DIM / 4
#define BLOCK 512
#define KMAX  5             // ceil(NV4/BLOCK); k<4 always valid, k==4 iff tid<452
#define RPB   8             // noise rows (s values) per block, same b
#define NBLK  (B_DIM * (S_DIM / RPB))   // 1024 blocks
#define NROWS (S_DIM * B_DIM)
#define NWAVE (BLOCK / 64)

// exp(theta+noise) = exp(theta)*exp(noise):  per-b T=exp(theta), V=T*y live in
// LDS (80 KB), so the inner loop issues ONE global stream (noise, 4 B/elem)
// instead of three (12 B/elem). Global request traffic 983 MB -> 338 MB.
// Per row:  S = sum T*e,  Q = sum (T*e)^2,  P = sum V*e,  e = exp(noise);
// loss_row = Q/S^2 - 2P/S + Y2_b,  Y2_b = sum y^2 (per b, computed once).
// Live state in phase 2 is 3 scalars -> no spill risk (R4/5/7 lesson: never
// pin big arrays, no min-wave launch_bounds clamp).
// Max-subtraction skipped: eta ~ N(0,sqrt(2)), dataset max ~8.5, exp safe in
// fp32; softmax shift-invariant.
__global__ __launch_bounds__(BLOCK) void perturbed_loss_lds(
    const float* __restrict__ theta,   // [B, D]
    const float* __restrict__ y,       // [B, D]
    const float* __restrict__ noise,   // [S, B, D]
    float4* __restrict__ partials,     // [NROWS] {S, Q, P, 0}
    float*  __restrict__ y2arr)        // [B_DIM]
{
    __shared__ float Tlds[D_DIM];      // 40000 B
    __shared__ float Vlds[D_DIM];      // 40000 B
    __shared__ float redS[2][NWAVE], redQ[2][NWAVE], redP[2][NWAVE];
    __shared__ float redY[NWAVE];

    const int blk  = blockIdx.x;       // [0, NBLK)
    const int b    = blk >> 3;         // [0,128): 8 consecutive blocks share b
    const int s0   = (blk & 7) * RPB;  // [0,64) step 8
    const int tid  = threadIdx.x;
    const int lane = tid & 63;
    const int wave = tid >> 6;

    const float4* th4 = reinterpret_cast<const float4*>(theta + (size_t)b * D_DIM);
    const float4* y4  = reinterpret_cast<const float4*>(y     + (size_t)b * D_DIM);
    float4* T4 = reinterpret_cast<float4*>(Tlds);
    float4* V4 = reinterpret_cast<float4*>(Vlds);

    // ---- Phase 1: T=exp(theta), V=T*y -> LDS; block Y2 ----
    float y2 = 0.0f;
    for (int i = tid; i < NV4; i += BLOCK) {
        float4 t  = th4[i];
        float4 yy = y4[i];
        float4 T, V;
        T.x = __expf(t.x); T.y = __expf(t.y);
        T.z = __expf(t.z); T.w = __expf(t.w);
        V.x = T.x * yy.x;  V.y = T.y * yy.y;
        V.z = T.z * yy.z;  V.w = T.w * yy.w;
        T4[i] = T;  V4[i] = V;
        y2 = fmaf(yy.x, yy.x, y2); y2 = fmaf(yy.y, yy.y, y2);
        y2 = fmaf(yy.z, yy.z, y2); y2 = fmaf(yy.w, yy.w, y2);
    }
    #pragma unroll
    for (int o = 32; o > 0; o >>= 1) y2 += __shfl_down(y2, o, 64);
    if (lane == 0) redY[wave] = y2;
    __syncthreads();                   // LDS T/V + redY ready
    if (tid == 0 && (blk & 7) == 0) {  // one writer per b
        float t = 0.0f;
        #pragma unroll
        for (int w = 0; w < NWAVE; ++w) t += redY[w];
        y2arr[b] = t;
    }

    // ---- Phase 2: stream RPB noise rows ----
    #pragma unroll 1
    for (int r = 0; r < RPB; ++r) {
        const int row = (s0 + r) * B_DIM + b;
        const float4* nz4 = reinterpret_cast<const float4*>(
            noise + (size_t)row * D_DIM);
        float s = 0.0f, q = 0.0f, p = 0.0f;
        #pragma unroll
        for (int k = 0; k < KMAX; ++k) {
            const int i = tid + k * BLOCK;
            if (k < KMAX - 1 || i < NV4) {
                float4 n = nz4[i];
                float4 T = T4[i];
                float4 V = V4[i];
                float e0 = __expf(n.x), e1 = __expf(n.y);
                float e2 = __expf(n.z), e3 = __expf(n.w);
                float t0 = T.x * e0, t1 = T.y * e1;
                float t2 = T.z * e2, t3 = T.w * e3;
                s += (t0 + t1) + (t2 + t3);
                q = fmaf(t0, t0, q); q = fmaf(t1, t1, q);
                q = fmaf(t2, t2, q); q = fmaf(t3, t3, q);
                p = fmaf(V.x, e0, p); p = fmaf(V.y, e1, p);
                p = fmaf(V.z, e2, p); p = fmaf(V.w, e3, p);
            }
        }
        #pragma unroll
        for (int o = 32; o > 0; o >>= 1) {
            s += __shfl_down(s, o, 64);
            q += __shfl_down(q, o, 64);
            p += __shfl_down(p, o, 64);
        }
        const int bb = r & 1;          // double-buffered red arrays:
        if (lane == 0) { redS[bb][wave] = s; redQ[bb][wave] = q; redP[bb][wave] = p; }
        __syncthreads();               // single barrier per row (see buffer proof)
        if (tid == 0) {
            float St = 0.0f, Qt = 0.0f, Pt = 0.0f;
            #pragma unroll
            for (int w = 0; w < NWAVE; ++w) {
                St += redS[bb][w]; Qt += redQ[bb][w]; Pt += redP[bb][w];
            }
            partials[row] = make_float4(St, Qt, Pt, 0.0f);
        }
        // buffer bb is re-written earliest at iter r+2, which all waves reach
        // only after barrier(r+1); tid0's read of bb precedes its barrier(r+1).
    }
}

// Deterministic fixed-order combine: per-row loss then global mean (double).
__global__ __launch_bounds__(256) void reduce_partials(
    const float4* __restrict__ partials,
    const float*  __restrict__ y2arr,
    float* __restrict__ out)
{
    __shared__ double red[4];
    const int tid  = threadIdx.x;
    const int lane = tid & 63;
    const int wave = tid >> 6;

    double acc = 0.0;
    for (int i = tid; i < NROWS; i += 256) {   // fixed order per thread
        float4 r = partials[i];
        double invS = 1.0 / (double)r.x;
        acc += ((double)r.y * invS - 2.0 * (double)r.z) * invS
             + (double)y2arr[i & (B_DIM - 1)];
    }
    #pragma unroll
    for (int o = 32; o > 0; o >>= 1) acc += __shfl_down(acc, o, 64);
    if (lane == 0) red[wave] = acc;
    __syncthreads();
    if (tid == 0) {
        double t = ((red[0] + red[1]) + (red[2] + red[3]));
        out[0] = (float)(t / ((double)S_DIM * (double)B_DIM * (double)D_DIM));
    }
}

extern "C" void kernel_launch(void* const* d_in, const int* in_sizes, int n_in,
                              void* d_out, int out_size, void* d_ws, size_t ws_size,
                              hipStream_t stream) {
    const float* theta = (const float*)d_in[0];
    const float* y     = (const float*)d_in[1];
    const float* noise = (const float*)d_in[2];
    float* out       = (float*)d_out;
    float4* partials = (float4*)d_ws;                       // 128 KB
    float*  y2arr    = (float*)((char*)d_ws + NROWS * sizeof(float4)); // 512 B

    perturbed_loss_lds<<<NBLK, BLOCK, 0, stream>>>(theta, y, noise,
                                                   partials, y2arr);
    reduce_partials<<<1, 256, 0, stream>>>(partials, y2arr, out);
}

// Round 10
// 80.924 us; speedup vs baseline: 1.2469x; 1.0047x over previous
//
#include <hip/hip_runtime.h>

#define S_DIM 64
#define B_DIM 128
#define D_DIM 10000
#define NV4   2500          // D_DIM / 4
#define BLOCK 512
#define RPB   8             // rows per block = waves per block (one row per wave)
#define NBLK  (B_DIM * (S_DIM / RPB))   // 1024 blocks
#define NROWS (S_DIM * B_DIM)
#define NWAVE (BLOCK / 64)
#define FULLIT 39           // 2500 = 39*64 + 4

// R9 scheme (exp(theta+noise) = exp(theta)*exp(noise), T/V tables in LDS,
// noise is the only bulk global stream: 4 B/elem) + R10 change: WAVE-per-row.
// Each of the 8 waves independently streams one noise row against the shared
// LDS tables -> no block barriers / no per-row load-issue bubbles in phase 2
// (R9 paid ~900cyc HBM latency + a 512-thread barrier at every row restart).
// Per row: S = sum T*e, Q = sum (T*e)^2, P = sum V*e, e = exp(noise);
// loss_row = Q/S^2 - 2P/S + Y2_b (Y2_b once per b). Live state: 3 scalars.
// Max-subtraction skipped: eta ~ N(0,sqrt(2)), dataset max ~8.5, exp safe in
// fp32; softmax shift-invariant. No min-wave clamp (R4/5 spill lesson).
__global__ __launch_bounds__(BLOCK) void perturbed_loss_waverow(
    const float* __restrict__ theta,   // [B, D]
    const float* __restrict__ y,       // [B, D]
    const float* __restrict__ noise,   // [S, B, D]
    float4* __restrict__ partials,     // [NROWS] {S, Q, P, 0}
    float*  __restrict__ y2arr)        // [B_DIM]
{
    __shared__ float Tlds[D_DIM];      // 40000 B
    __shared__ float Vlds[D_DIM];      // 40000 B
    __shared__ float redY[NWAVE];

    const int blk  = blockIdx.x;       // [0, NBLK)
    const int b    = blk >> 3;         // [0,128): 8 consecutive blocks share b
    const int s0   = (blk & 7) * RPB;  // [0,64) step 8
    const int tid  = threadIdx.x;
    const int lane = tid & 63;
    const int wave = tid >> 6;

    const float4* th4 = reinterpret_cast<const float4*>(theta + (size_t)b * D_DIM);
    const float4* y4  = reinterpret_cast<const float4*>(y     + (size_t)b * D_DIM);
    float4* T4 = reinterpret_cast<float4*>(Tlds);
    float4* V4 = reinterpret_cast<float4*>(Vlds);

    // ---- Phase 1 (block-cooperative): T=exp(theta), V=T*y -> LDS; Y2 ----
    float y2 = 0.0f;
    for (int i = tid; i < NV4; i += BLOCK) {
        float4 t  = th4[i];
        float4 yy = y4[i];
        float4 T, V;
        T.x = __expf(t.x); T.y = __expf(t.y);
        T.z = __expf(t.z); T.w = __expf(t.w);
        V.x = T.x * yy.x;  V.y = T.y * yy.y;
        V.z = T.z * yy.z;  V.w = T.w * yy.w;
        T4[i] = T;  V4[i] = V;
        y2 = fmaf(yy.x, yy.x, y2); y2 = fmaf(yy.y, yy.y, y2);
        y2 = fmaf(yy.z, yy.z, y2); y2 = fmaf(yy.w, yy.w, y2);
    }
    #pragma unroll
    for (int o = 32; o > 0; o >>= 1) y2 += __shfl_down(y2, o, 64);
    if (lane == 0) redY[wave] = y2;
    __syncthreads();                   // LDS T/V + redY ready (only barrier)
    if (tid == 0 && (blk & 7) == 0) {  // one writer per b
        float t = 0.0f;
        #pragma unroll
        for (int w = 0; w < NWAVE; ++w) t += redY[w];
        y2arr[b] = t;
    }

    // ---- Phase 2 (per-wave, independent): stream one noise row ----
    const int row = (s0 + wave) * B_DIM + b;
    const float4* nz4 = reinterpret_cast<const float4*>(noise + (size_t)row * D_DIM);

    float s = 0.0f, q = 0.0f, p = 0.0f;
    int i = lane;
    #pragma unroll 4
    for (int it = 0; it < FULLIT; ++it, i += 64) {
        float4 n = nz4[i];
        float4 T = T4[i];
        float4 V = V4[i];
        float e0 = __expf(n.x), e1 = __expf(n.y);
        float e2 = __expf(n.z), e3 = __expf(n.w);
        float t0 = T.x * e0, t1 = T.y * e1;
        float t2 = T.z * e2, t3 = T.w * e3;
        s += (t0 + t1) + (t2 + t3);
        q = fmaf(t0, t0, q); q = fmaf(t1, t1, q);
        q = fmaf(t2, t2, q); q = fmaf(t3, t3, q);
        p = fmaf(V.x, e0, p); p = fmaf(V.y, e1, p);
        p = fmaf(V.z, e2, p); p = fmaf(V.w, e3, p);
    }
    if (lane < 4) {                    // tail: elements 2496..2499 (float4)
        const int it = FULLIT * 64 + lane;
        float4 n = nz4[it];
        float4 T = T4[it];
        float4 V = V4[it];
        float e0 = __expf(n.x), e1 = __expf(n.y);
        float e2 = __expf(n.z), e3 = __expf(n.w);
        float t0 = T.x * e0, t1 = T.y * e1;
        float t2 = T.z * e2, t3 = T.w * e3;
        s += (t0 + t1) + (t2 + t3);
        q = fmaf(t0, t0, q); q = fmaf(t1, t1, q);
        q = fmaf(t2, t2, q); q = fmaf(t3, t3, q);
        p = fmaf(V.x, e0, p); p = fmaf(V.y, e1, p);
        p = fmaf(V.z, e2, p); p = fmaf(V.w, e3, p);
    }
    #pragma unroll
    for (int o = 32; o > 0; o >>= 1) {
        s += __shfl_down(s, o, 64);
        q += __shfl_down(q, o, 64);
        p += __shfl_down(p, o, 64);
    }
    if (lane == 0) partials[row] = make_float4(s, q, p, 0.0f);
}

// Deterministic fixed-order combine: per-row loss then global mean (double).
__global__ __launch_bounds__(256) void reduce_partials(
    const float4* __restrict__ partials,
    const float*  __restrict__ y2arr,
    float* __restrict__ out)
{
    __shared__ double red[4];
    const int tid  = threadIdx.x;
    const int lane = tid & 63;
    const int wave = tid >> 6;

    double acc = 0.0;
    for (int i = tid; i < NROWS; i += 256) {   // fixed order per thread
        float4 r = partials[i];
        double invS = 1.0 / (double)r.x;
        acc += ((double)r.y * invS - 2.0 * (double)r.z) * invS
             + (double)y2arr[i & (B_DIM - 1)];
    }
    #pragma unroll
    for (int o = 32; o > 0; o >>= 1) acc += __shfl_down(acc, o, 64);
    if (lane == 0) red[wave] = acc;
    __syncthreads();
    if (tid == 0) {
        double t = ((red[0] + red[1]) + (red[2] + red[3]));
        out[0] = (float)(t / ((double)S_DIM * (double)B_DIM * (double)D_DIM));
    }
}

extern "C" void kernel_launch(void* const* d_in, const int* in_sizes, int n_in,
                              void* d_out, int out_size, void* d_ws, size_t ws_size,
                              hipStream_t stream) {
    const float* theta = (const float*)d_in[0];
    const float* y     = (const float*)d_in[1];
    const float* noise = (const float*)d_in[2];
    float* out       = (float*)d_out;
    float4* partials = (float4*)d_ws;                       // 128 KB
    float*  y2arr    = (float*)((char*)d_ws + NROWS * sizeof(float4)); // 512 B

    perturbed_loss_waverow<<<NBLK, BLOCK, 0, stream>>>(theta, y, noise,
                                                       partials, y2arr);
    reduce_partials<<<1, 256, 0, stream>>>(partials, y2arr, out);
}

// Round 11
// 73.070 us; speedup vs baseline: 1.3809x; 1.1075x over previous
//
#include <hip/hip_runtime.h>

#define S_DIM 64
#define B_DIM 128
#define D_DIM 10000
#define NV4   2500          // D_DIM / 4
#define BLOCK 512
#define RPB   8             // rows per block = one row per wave
#define NBLK  (B_DIM * (S_DIM / RPB))   // 1024 blocks
#define NROWS (S_DIM * B_DIM)
#define NWAVE (BLOCK / 64)
#define FULLIT 39           // 2500 = 39*64 + 4

// bf16 pack/unpack (RNE rounding; lo in bits[15:0], hi in bits[31:16])
static __device__ __forceinline__ unsigned bf16pack(float lo, float hi) {
    unsigned a = __builtin_bit_cast(unsigned, lo);
    unsigned b = __builtin_bit_cast(unsigned, hi);
    a = (a + 0x7fffu + ((a >> 16) & 1u)) >> 16;
    b = (b + 0x7fffu + ((b >> 16) & 1u)) & 0xffff0000u;
    return (a & 0xffffu) | b;
}
static __device__ __forceinline__ float bf16lo(unsigned u) {
    return __builtin_bit_cast(float, u << 16);
}
static __device__ __forceinline__ float bf16hi(unsigned u) {
    return __builtin_bit_cast(float, u & 0xffff0000u);
}

// R10 structure (wave-per-row, LDS tables, noise = only bulk global stream)
// + R11: bf16-packed tables halve LDS (80->40KB) -> 4 blocks/CU = 32 waves/CU
// (launch_bounds(512,8) forces <=64 VGPR; phase-2 live state ~30 regs), and
// one ds_read_b128/iter instead of two. T-hat rounding cancels in P/S ratio;
// W = rnd(T-hat * y) enters 2P/S (~1.0) at ~1e-4 — threshold is 6.7e-3.
// Per row: S = sum T*e, Q = sum (T*e)^2, P = sum W*e, e = exp(noise);
// loss_row = Q/S^2 - 2P/S + Y2_b. Wave folds its row's loss to double;
// block writes ONE double (k2 tail shrinks to ~1-2us, memset node dropped).
__global__ __launch_bounds__(BLOCK, 8) void perturbed_loss_waverow(
    const float* __restrict__ theta,   // [B, D]
    const float* __restrict__ y,       // [B, D]
    const float* __restrict__ noise,   // [S, B, D]
    double* __restrict__ blockloss,    // [NBLK]
    float*  __restrict__ y2arr)        // [B_DIM]
{
    __shared__ uint4  TV[NV4];         // 40000 B: {T01,T23,W01,W23} bf16-packed
    __shared__ float  redY[NWAVE];
    __shared__ double wloss[NWAVE];

    const int blk  = blockIdx.x;       // [0, NBLK)
    const int b    = blk >> 3;         // [0,128): 8 consecutive blocks share b
    const int s0   = (blk & 7) * RPB;  // [0,64) step 8
    const int tid  = threadIdx.x;
    const int lane = tid & 63;
    const int wave = tid >> 6;

    const float4* th4 = reinterpret_cast<const float4*>(theta + (size_t)b * D_DIM);
    const float4* y4  = reinterpret_cast<const float4*>(y     + (size_t)b * D_DIM);

    // ---- Phase 1: T=rnd_bf16(exp(theta)), W=rnd_bf16(T*y) -> LDS; Y2 ----
    float y2 = 0.0f;
    for (int i = tid; i < NV4; i += BLOCK) {
        float4 t  = th4[i];
        float4 yy = y4[i];
        unsigned tp0 = bf16pack(__expf(t.x), __expf(t.y));
        unsigned tp1 = bf16pack(__expf(t.z), __expf(t.w));
        unsigned wp0 = bf16pack(bf16lo(tp0) * yy.x, bf16hi(tp0) * yy.y);
        unsigned wp1 = bf16pack(bf16lo(tp1) * yy.z, bf16hi(tp1) * yy.w);
        TV[i] = make_uint4(tp0, tp1, wp0, wp1);
        y2 = fmaf(yy.x, yy.x, y2); y2 = fmaf(yy.y, yy.y, y2);
        y2 = fmaf(yy.z, yy.z, y2); y2 = fmaf(yy.w, yy.w, y2);
    }
    #pragma unroll
    for (int o = 32; o > 0; o >>= 1) y2 += __shfl_down(y2, o, 64);
    if (lane == 0) redY[wave] = y2;
    __syncthreads();                   // LDS TV + redY ready
    if (tid == 0 && (blk & 7) == 0) {  // one writer per b
        float t = 0.0f;
        #pragma unroll
        for (int w = 0; w < NWAVE; ++w) t += redY[w];
        y2arr[b] = t;
    }

    // ---- Phase 2 (per-wave, independent): stream one noise row ----
    const int row = (s0 + wave) * B_DIM + b;
    const float4* nz4 = reinterpret_cast<const float4*>(noise + (size_t)row * D_DIM);

    float s = 0.0f, q = 0.0f, p = 0.0f;
    int i = lane;
    #pragma unroll 2
    for (int it = 0; it < FULLIT; ++it, i += 64) {
        float4 n = nz4[i];
        uint4  u = TV[i];
        float e0 = __expf(n.x), e1 = __expf(n.y);
        float e2 = __expf(n.z), e3 = __expf(n.w);
        float t0 = bf16lo(u.x) * e0, t1 = bf16hi(u.x) * e1;
        float t2 = bf16lo(u.y) * e2, t3 = bf16hi(u.y) * e3;
        s += (t0 + t1) + (t2 + t3);
        q = fmaf(t0, t0, q); q = fmaf(t1, t1, q);
        q = fmaf(t2, t2, q); q = fmaf(t3, t3, q);
        p = fmaf(bf16lo(u.z), e0, p); p = fmaf(bf16hi(u.z), e1, p);
        p = fmaf(bf16lo(u.w), e2, p); p = fmaf(bf16hi(u.w), e3, p);
    }
    if (lane < 4) {                    // tail: float4 elements 2496..2499
        const int j = FULLIT * 64 + lane;
        float4 n = nz4[j];
        uint4  u = TV[j];
        float e0 = __expf(n.x), e1 = __expf(n.y);
        float e2 = __expf(n.z), e3 = __expf(n.w);
        float t0 = bf16lo(u.x) * e0, t1 = bf16hi(u.x) * e1;
        float t2 = bf16lo(u.y) * e2, t3 = bf16hi(u.y) * e3;
        s += (t0 + t1) + (t2 + t3);
        q = fmaf(t0, t0, q); q = fmaf(t1, t1, q);
        q = fmaf(t2, t2, q); q = fmaf(t3, t3, q);
        p = fmaf(bf16lo(u.z), e0, p); p = fmaf(bf16hi(u.z), e1, p);
        p = fmaf(bf16lo(u.w), e2, p); p = fmaf(bf16hi(u.w), e3, p);
    }
    #pragma unroll
    for (int o = 32; o > 0; o >>= 1) {
        s += __shfl_down(s, o, 64);
        q += __shfl_down(q, o, 64);
        p += __shfl_down(p, o, 64);
    }
    if (lane == 0) {                   // fold this row's loss terms (double)
        double invS = 1.0 / (double)s;
        wloss[wave] = ((double)q * invS - 2.0 * (double)p) * invS;
    }
    __syncthreads();
    if (tid == 0) {
        double t = 0.0;
        #pragma unroll
        for (int w = 0; w < NWAVE; ++w) t += wloss[w];
        blockloss[blk] = t;
    }
}

// Deterministic fixed-order final combine (1024 doubles + 128 y2 floats).
__global__ __launch_bounds__(256) void reduce_final(
    const double* __restrict__ blockloss,
    const float*  __restrict__ y2arr,
    float* __restrict__ out)
{
    __shared__ double red[4];
    const int tid  = threadIdx.x;
    const int lane = tid & 63;
    const int wave = tid >> 6;

    double acc = 0.0;
    for (int i = tid; i < NBLK; i += 256) acc += blockloss[i];
    if (tid < B_DIM) acc += (double)S_DIM * (double)y2arr[tid];
    #pragma unroll
    for (int o = 32; o > 0; o >>= 1) acc += __shfl_down(acc, o, 64);
    if (lane == 0) red[wave] = acc;
    __syncthreads();
    if (tid == 0) {
        double t = ((red[0] + red[1]) + (red[2] + red[3]));
        out[0] = (float)(t / ((double)S_DIM * (double)B_DIM * (double)D_DIM));
    }
}

extern "C" void kernel_launch(void* const* d_in, const int* in_sizes, int n_in,
                              void* d_out, int out_size, void* d_ws, size_t ws_size,
                              hipStream_t stream) {
    const float* theta = (const float*)d_in[0];
    const float* y     = (const float*)d_in[1];
    const float* noise = (const float*)d_in[2];
    float* out        = (float*)d_out;
    double* blockloss = (double*)d_ws;                          // 8 KB
    float*  y2arr     = (float*)((char*)d_ws + NBLK * sizeof(double)); // 512 B

    perturbed_loss_waverow<<<NBLK, BLOCK, 0, stream>>>(theta, y, noise,
                                                       blockloss, y2arr);
    reduce_final<<<1, 256, 0, stream>>>(blockloss, y2arr, out);
}

// Round 12
// 67.691 us; speedup vs baseline: 1.4906x; 1.0795x over previous
//
#include <hip/hip_runtime.h>

#define S_DIM 64
#define B_DIM 128
#define D_DIM 10000
#define NV4   2500          // D_DIM / 4
#define BLOCK 512
#define RPB   8             // rows per block = one row per wave
#define NBLK  (B_DIM * (S_DIM / RPB))   // 1024 blocks
#define NROWS (S_DIM * B_DIM)
#define NWAVE (BLOCK / 64)
#define FULLIT 39           // 2500 = 39*64 + 4

// bf16 pack/unpack (RNE rounding; lo in bits[15:0], hi in bits[31:16])
static __device__ __forceinline__ unsigned bf16pack(float lo, float hi) {
    unsigned a = __builtin_bit_cast(unsigned, lo);
    unsigned b = __builtin_bit_cast(unsigned, hi);
    a = (a + 0x7fffu + ((a >> 16) & 1u)) >> 16;
    b = (b + 0x7fffu + ((b >> 16) & 1u)) & 0xffff0000u;
    return (a & 0xffffu) | b;
}
static __device__ __forceinline__ float bf16lo(unsigned u) {
    return __builtin_bit_cast(float, u << 16);
}
static __device__ __forceinline__ float bf16hi(unsigned u) {
    return __builtin_bit_cast(float, u & 0xffff0000u);
}

// R11 structure (wave-per-row, bf16 LDS tables, 32 waves/CU) + R12: XCD-aware
// block->(b,s0) swizzle. Old mapping put the 8 blocks sharing b on all 8 XCDs
// (round-robin), so every XCD pulled ALL 128 theta/y rows (10.24 MB > 4 MB L2)
// -> ~82 MB redundant HBM fetches (~13us). New mapping keeps blk%8 constant
// per b: b = (blk>>6)*8 + (blk&7), so each XCD owns 16 b values (1.28 MB,
// L2-resident) and theta/y are fetched from HBM once chip-wide.
// Per row: S = sum T*e, Q = sum (T*e)^2, P = sum W*e, e = exp(noise);
// loss_row = Q/S^2 - 2P/S + Y2_b. Max-subtraction skipped (eta ~ N(0,sqrt2),
// dataset max ~8.5, exp safe in fp32; softmax shift-invariant).
__global__ __launch_bounds__(BLOCK, 8) void perturbed_loss_waverow(
    const float* __restrict__ theta,   // [B, D]
    const float* __restrict__ y,       // [B, D]
    const float* __restrict__ noise,   // [S, B, D]
    double* __restrict__ blockloss,    // [NBLK]
    float*  __restrict__ y2arr)        // [B_DIM]
{
    __shared__ uint4  TV[NV4];         // 40000 B: {T01,T23,W01,W23} bf16-packed
    __shared__ float  redY[NWAVE];
    __shared__ double wloss[NWAVE];

    const int blk  = blockIdx.x;           // [0, NBLK)
    const int b    = ((blk >> 6) << 3) + (blk & 7);  // [0,128); blk%8 fixed per b
    const int s0   = ((blk >> 3) & 7) * RPB;         // [0,64) step 8
    const int tid  = threadIdx.x;
    const int lane = tid & 63;
    const int wave = tid >> 6;

    const float4* th4 = reinterpret_cast<const float4*>(theta + (size_t)b * D_DIM);
    const float4* y4  = reinterpret_cast<const float4*>(y     + (size_t)b * D_DIM);

    // ---- Phase 1: T=rnd_bf16(exp(theta)), W=rnd_bf16(T*y) -> LDS; Y2 ----
    float y2 = 0.0f;
    for (int i = tid; i < NV4; i += BLOCK) {
        float4 t  = th4[i];
        float4 yy = y4[i];
        unsigned tp0 = bf16pack(__expf(t.x), __expf(t.y));
        unsigned tp1 = bf16pack(__expf(t.z), __expf(t.w));
        unsigned wp0 = bf16pack(bf16lo(tp0) * yy.x, bf16hi(tp0) * yy.y);
        unsigned wp1 = bf16pack(bf16lo(tp1) * yy.z, bf16hi(tp1) * yy.w);
        TV[i] = make_uint4(tp0, tp1, wp0, wp1);
        y2 = fmaf(yy.x, yy.x, y2); y2 = fmaf(yy.y, yy.y, y2);
        y2 = fmaf(yy.z, yy.z, y2); y2 = fmaf(yy.w, yy.w, y2);
    }
    #pragma unroll
    for (int o = 32; o > 0; o >>= 1) y2 += __shfl_down(y2, o, 64);
    if (lane == 0) redY[wave] = y2;
    __syncthreads();                   // LDS TV + redY ready
    if (tid == 0 && ((blk >> 3) & 7) == 0) {  // one writer per b
        float t = 0.0f;
        #pragma unroll
        for (int w = 0; w < NWAVE; ++w) t += redY[w];
        y2arr[b] = t;
    }

    // ---- Phase 2 (per-wave, independent): stream one noise row ----
    const int row = (s0 + wave) * B_DIM + b;
    const float4* nz4 = reinterpret_cast<const float4*>(noise + (size_t)row * D_DIM);

    float s = 0.0f, q = 0.0f, p = 0.0f;
    int i = lane;
    #pragma unroll 2
    for (int it = 0; it < FULLIT; ++it, i += 64) {
        float4 n = nz4[i];
        uint4  u = TV[i];
        float e0 = __expf(n.x), e1 = __expf(n.y);
        float e2 = __expf(n.z), e3 = __expf(n.w);
        float t0 = bf16lo(u.x) * e0, t1 = bf16hi(u.x) * e1;
        float t2 = bf16lo(u.y) * e2, t3 = bf16hi(u.y) * e3;
        s += (t0 + t1) + (t2 + t3);
        q = fmaf(t0, t0, q); q = fmaf(t1, t1, q);
        q = fmaf(t2, t2, q); q = fmaf(t3, t3, q);
        p = fmaf(bf16lo(u.z), e0, p); p = fmaf(bf16hi(u.z), e1, p);
        p = fmaf(bf16lo(u.w), e2, p); p = fmaf(bf16hi(u.w), e3, p);
    }
    if (lane < 4) {                    // tail: float4 elements 2496..2499
        const int j = FULLIT * 64 + lane;
        float4 n = nz4[j];
        uint4  u = TV[j];
        float e0 = __expf(n.x), e1 = __expf(n.y);
        float e2 = __expf(n.z), e3 = __expf(n.w);
        float t0 = bf16lo(u.x) * e0, t1 = bf16hi(u.x) * e1;
        float t2 = bf16lo(u.y) * e2, t3 = bf16hi(u.y) * e3;
        s += (t0 + t1) + (t2 + t3);
        q = fmaf(t0, t0, q); q = fmaf(t1, t1, q);
        q = fmaf(t2, t2, q); q = fmaf(t3, t3, q);
        p = fmaf(bf16lo(u.z), e0, p); p = fmaf(bf16hi(u.z), e1, p);
        p = fmaf(bf16lo(u.w), e2, p); p = fmaf(bf16hi(u.w), e3, p);
    }
    #pragma unroll
    for (int o = 32; o > 0; o >>= 1) {
        s += __shfl_down(s, o, 64);
        q += __shfl_down(q, o, 64);
        p += __shfl_down(p, o, 64);
    }
    if (lane == 0) {                   // fold this row's loss terms (double)
        double invS = 1.0 / (double)s;
        wloss[wave] = ((double)q * invS - 2.0 * (double)p) * invS;
    }
    __syncthreads();
    if (tid == 0) {
        double t = 0.0;
        #pragma unroll
        for (int w = 0; w < NWAVE; ++w) t += wloss[w];
        blockloss[blk] = t;
    }
}

// Deterministic fixed-order final combine (1024 doubles + 128 y2 floats).
__global__ __launch_bounds__(256) void reduce_final(
    const double* __restrict__ blockloss,
    const float*  __restrict__ y2arr,
    float* __restrict__ out)
{
    __shared__ double red[4];
    const int tid  = threadIdx.x;
    const int lane = tid & 63;
    const int wave = tid >> 6;

    double acc = 0.0;
    for (int i = tid; i < NBLK; i += 256) acc += blockloss[i];
    if (tid < B_DIM) acc += (double)S_DIM * (double)y2arr[tid];
    #pragma unroll
    for (int o = 32; o > 0; o >>= 1) acc += __shfl_down(acc, o, 64);
    if (lane == 0) red[wave] = acc;
    __syncthreads();
    if (tid == 0) {
        double t = ((red[0] + red[1]) + (red[2] + red[3]));
        out[0] = (float)(t / ((double)S_DIM * (double)B_DIM * (double)D_DIM));
    }
}

extern "C" void kernel_launch(void* const* d_in, const int* in_sizes, int n_in,
                              void* d_out, int out_size, void* d_ws, size_t ws_size,
                              hipStream_t stream) {
    const float* theta = (const float*)d_in[0];
    const float* y     = (const float*)d_in[1];
    const float* noise = (const float*)d_in[2];
    float* out        = (float*)d_out;
    double* blockloss = (double*)d_ws;                          // 8 KB
    float*  y2arr     = (float*)((char*)d_ws + NBLK * sizeof(double)); // 512 B

    perturbed_loss_waverow<<<NBLK, BLOCK, 0, stream>>>(theta, y, noise,
                                                       blockloss, y2arr);
    reduce_final<<<1, 256, 0, stream>>>(blockloss, y2arr, out);
}

// Round 13
// 67.662 us; speedup vs baseline: 1.4912x; 1.0004x over previous
//
#include <hip/hip_runtime.h>

#define S_DIM 64
#define B_DIM 128
#define D_DIM 10000
#define NV4   2500          // D_DIM / 4
#define BLOCK 512
#define RPB   8             // rows per block = one row per wave
#define NBLK  (B_DIM * (S_DIM / RPB))   // 1024 blocks
#define NROWS (S_DIM * B_DIM)
#define NWAVE (BLOCK / 64)
#define FULLIT 39           // 2500 = 39*64 + 4

// bf16 pack/unpack (RNE rounding; lo in bits[15:0], hi in bits[31:16])
static __device__ __forceinline__ unsigned bf16pack(float lo, float hi) {
    unsigned a = __builtin_bit_cast(unsigned, lo);
    unsigned b = __builtin_bit_cast(unsigned, hi);
    a = (a + 0x7fffu + ((a >> 16) & 1u)) >> 16;
    b = (b + 0x7fffu + ((b >> 16) & 1u)) & 0xffff0000u;
    return (a & 0xffffu) | b;
}
static __device__ __forceinline__ float bf16lo(unsigned u) {
    return __builtin_bit_cast(float, u << 16);
}
static __device__ __forceinline__ float bf16hi(unsigned u) {
    return __builtin_bit_cast(float, u & 0xffff0000u);
}

// R12 structure (wave-per-row, bf16 LDS tables, 32 waves/CU, XCD swizzle so
// the 8 blocks sharing b land on one XCD -> theta/y L2-resident).
// R13: phase-2 unroll 2 -> 4. MLP arithmetic: need ~10 B/cyc/CU at ~500-900cy
// latency => ~5-9 KB in flight/CU; unroll 2 gave only 1 KB (32 waves x 2 x
// 16 B). Unroll 4 doubles in-flight bytes and gives 4 independent
// global_load_dwordx4 + 4 ds_read_b128 per wave group. ~50 live VGPR < 64.
// Per row: S = sum T*e, Q = sum (T*e)^2, P = sum W*e, e = exp(noise);
// loss_row = Q/S^2 - 2P/S + Y2_b. Max-subtraction skipped (eta ~ N(0,sqrt2),
// dataset max ~8.5, exp safe in fp32; softmax shift-invariant).
__global__ __launch_bounds__(BLOCK, 8) void perturbed_loss_waverow(
    const float* __restrict__ theta,   // [B, D]
    const float* __restrict__ y,       // [B, D]
    const float* __restrict__ noise,   // [S, B, D]
    double* __restrict__ blockloss,    // [NBLK]
    float*  __restrict__ y2arr)        // [B_DIM]
{
    __shared__ uint4  TV[NV4];         // 40000 B: {T01,T23,W01,W23} bf16-packed
    __shared__ float  redY[NWAVE];
    __shared__ double wloss[NWAVE];

    const int blk  = blockIdx.x;           // [0, NBLK)
    const int b    = ((blk >> 6) << 3) + (blk & 7);  // [0,128); blk%8 fixed per b
    const int s0   = ((blk >> 3) & 7) * RPB;         // [0,64) step 8
    const int tid  = threadIdx.x;
    const int lane = tid & 63;
    const int wave = tid >> 6;

    const float4* th4 = reinterpret_cast<const float4*>(theta + (size_t)b * D_DIM);
    const float4* y4  = reinterpret_cast<const float4*>(y     + (size_t)b * D_DIM);

    // ---- Phase 1: T=rnd_bf16(exp(theta)), W=rnd_bf16(T*y) -> LDS; Y2 ----
    float y2 = 0.0f;
    for (int i = tid; i < NV4; i += BLOCK) {
        float4 t  = th4[i];
        float4 yy = y4[i];
        unsigned tp0 = bf16pack(__expf(t.x), __expf(t.y));
        unsigned tp1 = bf16pack(__expf(t.z), __expf(t.w));
        unsigned wp0 = bf16pack(bf16lo(tp0) * yy.x, bf16hi(tp0) * yy.y);
        unsigned wp1 = bf16pack(bf16lo(tp1) * yy.z, bf16hi(tp1) * yy.w);
        TV[i] = make_uint4(tp0, tp1, wp0, wp1);
        y2 = fmaf(yy.x, yy.x, y2); y2 = fmaf(yy.y, yy.y, y2);
        y2 = fmaf(yy.z, yy.z, y2); y2 = fmaf(yy.w, yy.w, y2);
    }
    #pragma unroll
    for (int o = 32; o > 0; o >>= 1) y2 += __shfl_down(y2, o, 64);
    if (lane == 0) redY[wave] = y2;
    __syncthreads();                   // LDS TV + redY ready
    if (tid == 0 && ((blk >> 3) & 7) == 0) {  // one writer per b
        float t = 0.0f;
        #pragma unroll
        for (int w = 0; w < NWAVE; ++w) t += redY[w];
        y2arr[b] = t;
    }

    // ---- Phase 2 (per-wave, independent): stream one noise row ----
    const int row = (s0 + wave) * B_DIM + b;
    const float4* nz4 = reinterpret_cast<const float4*>(noise + (size_t)row * D_DIM);

    float s = 0.0f, q = 0.0f, p = 0.0f;
    int i = lane;
    #pragma unroll 4
    for (int it = 0; it < FULLIT; ++it, i += 64) {
        float4 n = nz4[i];
        uint4  u = TV[i];
        float e0 = __expf(n.x), e1 = __expf(n.y);
        float e2 = __expf(n.z), e3 = __expf(n.w);
        float t0 = bf16lo(u.x) * e0, t1 = bf16hi(u.x) * e1;
        float t2 = bf16lo(u.y) * e2, t3 = bf16hi(u.y) * e3;
        s += (t0 + t1) + (t2 + t3);
        q = fmaf(t0, t0, q); q = fmaf(t1, t1, q);
        q = fmaf(t2, t2, q); q = fmaf(t3, t3, q);
        p = fmaf(bf16lo(u.z), e0, p); p = fmaf(bf16hi(u.z), e1, p);
        p = fmaf(bf16lo(u.w), e2, p); p = fmaf(bf16hi(u.w), e3, p);
    }
    if (lane < 4) {                    // tail: float4 elements 2496..2499
        const int j = FULLIT * 64 + lane;
        float4 n = nz4[j];
        uint4  u = TV[j];
        float e0 = __expf(n.x), e1 = __expf(n.y);
        float e2 = __expf(n.z), e3 = __expf(n.w);
        float t0 = bf16lo(u.x) * e0, t1 = bf16hi(u.x) * e1;
        float t2 = bf16lo(u.y) * e2, t3 = bf16hi(u.y) * e3;
        s += (t0 + t1) + (t2 + t3);
        q = fmaf(t0, t0, q); q = fmaf(t1, t1, q);
        q = fmaf(t2, t2, q); q = fmaf(t3, t3, q);
        p = fmaf(bf16lo(u.z), e0, p); p = fmaf(bf16hi(u.z), e1, p);
        p = fmaf(bf16lo(u.w), e2, p); p = fmaf(bf16hi(u.w), e3, p);
    }
    #pragma unroll
    for (int o = 32; o > 0; o >>= 1) {
        s += __shfl_down(s, o, 64);
        q += __shfl_down(q, o, 64);
        p += __shfl_down(p, o, 64);
    }
    if (lane == 0) {                   // fold this row's loss terms (double)
        double invS = 1.0 / (double)s;
        wloss[wave] = ((double)q * invS - 2.0 * (double)p) * invS;
    }
    __syncthreads();
    if (tid == 0) {
        double t = 0.0;
        #pragma unroll
        for (int w = 0; w < NWAVE; ++w) t += wloss[w];
        blockloss[blk] = t;
    }
}

// Deterministic fixed-order final combine (1024 doubles + 128 y2 floats).
__global__ __launch_bounds__(256) void reduce_final(
    const double* __restrict__ blockloss,
    const float*  __restrict__ y2arr,
    float* __restrict__ out)
{
    __shared__ double red[4];
    const int tid  = threadIdx.x;
    const int lane = tid & 63;
    const int wave = tid >> 6;

    double acc = 0.0;
    for (int i = tid; i < NBLK; i += 256) acc += blockloss[i];
    if (tid < B_DIM) acc += (double)S_DIM * (double)y2arr[tid];
    #pragma unroll
    for (int o = 32; o > 0; o >>= 1) acc += __shfl_down(acc, o, 64);
    if (lane == 0) red[wave] = acc;
    __syncthreads();
    if (tid == 0) {
        double t = ((red[0] + red[1]) + (red[2] + red[3]));
        out[0] = (float)(t / ((double)S_DIM * (double)B_DIM * (double)D_DIM));
    }
}

extern "C" void kernel_launch(void* const* d_in, const int* in_sizes, int n_in,
                              void* d_out, int out_size, void* d_ws, size_t ws_size,
                              hipStream_t stream) {
    const float* theta = (const float*)d_in[0];
    const float* y     = (const float*)d_in[1];
    const float* noise = (const float*)d_in[2];
    float* out        = (float*)d_out;
    double* blockloss = (double*)d_ws;                          // 8 KB
    float*  y2arr     = (float*)((char*)d_ws + NBLK * sizeof(double)); // 512 B

    perturbed_loss_waverow<<<NBLK, BLOCK, 0, stream>>>(theta, y, noise,
                                                       blockloss, y2arr);
    reduce_final<<<1, 256, 0, stream>>>(blockloss, y2arr, out);
}